// Round 3
// baseline (227.779 us; speedup 1.0000x reference)
//
#include <hip/hip_runtime.h>
#include <math.h>

namespace {

constexpr int RAD  = 6;
constexpr int P    = 13;
constexpr int NWIN = 169;   // P*P
constexpr int NTOT = 338;   // 2 refs * NWIN
constexpr int NCH  = 128;
constexpr int NCLS = 32;
constexpr int W    = 64;
constexpr int HW   = 4096;
constexpr float FOUR_LN2 = 2.772588722239781f;

__device__ __forceinline__ bool better(float va, int ia, float vb, int ib) {
  return (va > vb) || ((va == vb) && (ia < ib));
}

__global__ __launch_bounds__(384) void colorizer_kernel(
    const float* __restrict__ fr,   // [2][2][128][64][64]  (nref,b,c,y,x)
    const float* __restrict__ ft,   // [2][128][64][64]
    const int*  __restrict__ q,     // [2][2][1][256][256]
    float* __restrict__ out) {      // [2][32][64][64]
  const int pix = blockIdx.x;          // b*4096 + y*64 + x
  const int b = pix >> 12;
  const int y = (pix >> 6) & 63;
  const int x = pix & 63;
  const int t = threadIdx.x;
  const int wid  = t >> 6;
  const int lane = t & 63;

  __shared__ float s[NTOT];
  __shared__ float wred[6];
  __shared__ float accS[NCLS];
  __shared__ float params[2][8];  // per ref: flag, w0, xs0, ys0, w1, xs1, ys1

  if (t < NCLS) accS[t] = 0.f;

  const bool act = (t < NTOT);
  const int i  = (t >= NWIN) ? 1 : 0;
  const int m  = t - i * NWIN;          // 0..168 (garbage ok for t>=338)
  const int dy = m / P;
  const int dx = m - dy * P;
  const int yy = y + dy - RAD;
  const int xx = x + dx - RAD;
  const bool inb = ((unsigned)yy < 64u) && ((unsigned)xx < 64u);

  // ---------- phase 1: correlation dots ----------
  // ft address is block-uniform -> scalar (SGPR) loads, no LDS staging.
  // fr loads: 16 independent loads per group to maximize loads-in-flight.
  float dot = 0.f;
  if (act && inb) {
    const float* __restrict__ rp = fr + (size_t)((i * 2 + b) * NCH) * HW + yy * W + xx;
    const float* __restrict__ tp = ft + (size_t)(b * NCH) * HW + y * W + x;
    float a0 = 0.f, a1 = 0.f, a2 = 0.f, a3 = 0.f,
          a4 = 0.f, a5 = 0.f, a6 = 0.f, a7 = 0.f;
    #pragma unroll
    for (int c0 = 0; c0 < NCH; c0 += 16) {
      float r[16];
      #pragma unroll
      for (int k = 0; k < 16; ++k) r[k] = rp[(size_t)(c0 + k) * HW];
      a0 = fmaf(tp[(size_t)(c0 +  0) * HW], r[ 0], a0);
      a1 = fmaf(tp[(size_t)(c0 +  1) * HW], r[ 1], a1);
      a2 = fmaf(tp[(size_t)(c0 +  2) * HW], r[ 2], a2);
      a3 = fmaf(tp[(size_t)(c0 +  3) * HW], r[ 3], a3);
      a4 = fmaf(tp[(size_t)(c0 +  4) * HW], r[ 4], a4);
      a5 = fmaf(tp[(size_t)(c0 +  5) * HW], r[ 5], a5);
      a6 = fmaf(tp[(size_t)(c0 +  6) * HW], r[ 6], a6);
      a7 = fmaf(tp[(size_t)(c0 +  7) * HW], r[ 7], a7);
      a0 = fmaf(tp[(size_t)(c0 +  8) * HW], r[ 8], a0);
      a1 = fmaf(tp[(size_t)(c0 +  9) * HW], r[ 9], a1);
      a2 = fmaf(tp[(size_t)(c0 + 10) * HW], r[10], a2);
      a3 = fmaf(tp[(size_t)(c0 + 11) * HW], r[11], a3);
      a4 = fmaf(tp[(size_t)(c0 + 12) * HW], r[12], a4);
      a5 = fmaf(tp[(size_t)(c0 + 13) * HW], r[13], a5);
      a6 = fmaf(tp[(size_t)(c0 + 14) * HW], r[14], a6);
      a7 = fmaf(tp[(size_t)(c0 + 15) * HW], r[15], a7);
    }
    dot = ((a0 + a1) + (a2 + a3)) + ((a4 + a5) + (a6 + a7));
  }

  // ---------- phase 2: joint softmax over 338 ----------
  const float v = act ? dot : -INFINITY;
  float lmax = v;
  for (int off = 32; off > 0; off >>= 1)
    lmax = fmaxf(lmax, __shfl_xor(lmax, off));
  if (lane == 0) wred[wid] = lmax;
  __syncthreads();
  const float gmax = fmaxf(fmaxf(fmaxf(wred[0], wred[1]), fmaxf(wred[2], wred[3])),
                           fmaxf(wred[4], wred[5]));
  const float e = act ? __expf(v - gmax) : 0.f;
  float lsum = e;
  for (int off = 32; off > 0; off >>= 1)
    lsum += __shfl_xor(lsum, off);
  __syncthreads();              // everyone done reading wred (gmax)
  if (lane == 0) wred[wid] = lsum;
  __syncthreads();
  const float gsum = wred[0] + wred[1] + wred[2] + wred[3] + wred[4] + wred[5];
  const float prob = e / gsum;
  if (act) s[t] = prob;
  __syncthreads();

  // ---------- phase 3: per-ref top-2 (waves 0,1), stable tie-break ----------
  if (wid < 2) {
    const int ii = wid;
    float v1 = -1.f, v2 = -1.f;
    int i1 = 1 << 20, i2 = 1 << 20;
    for (int mm = lane; mm < NWIN; mm += 64) {
      const float pv = s[ii * NWIN + mm];
      if (better(pv, mm, v1, i1)) { v2 = v1; i2 = i1; v1 = pv; i1 = mm; }
      else if (better(pv, mm, v2, i2)) { v2 = pv; i2 = mm; }
    }
    for (int off = 32; off > 0; off >>= 1) {
      const float u1 = __shfl_xor(v1, off); const int j1 = __shfl_xor(i1, off);
      const float u2 = __shfl_xor(v2, off); const int j2 = __shfl_xor(i2, off);
      if (better(u1, j1, v1, i1)) {
        float nv2; int ni2;
        if (better(v1, i1, u2, j2)) { nv2 = v1; ni2 = i1; }
        else                        { nv2 = u2; ni2 = j2; }
        v1 = u1; i1 = j1; v2 = nv2; i2 = ni2;
      } else if (better(u1, j1, v2, i2)) {
        v2 = u1; i2 = j1;
      }
    }
    if (lane == 0) {
      const float e1 = __expf(v1);
      const float e2 = __expf(v2);
      const float rs = 1.f / (e1 + e2);
      params[ii][0] = (v1 > 0.1f) ? 1.f : 0.f;
      params[ii][1] = e1 * rs;                 // w0
      params[ii][2] = (float)(i1 % P);         // xs0
      params[ii][3] = (float)(i1 / P);         // ys0
      params[ii][4] = e2 * rs;                 // w1
      params[ii][5] = (float)(i2 % P);         // xs1
      params[ii][6] = (float)(i2 / P);         // ys1
    }
  }
  __syncthreads();

  // ---------- phase 4: corr2 + label scatter ----------
  if (act) {
    float val;
    if (params[i][0] != 0.f) {
      const float fdx0 = (float)dx - params[i][2];
      const float fdy0 = (float)dy - params[i][3];
      const float fdx1 = (float)dx - params[i][5];
      const float fdy1 = (float)dy - params[i][6];
      val = params[i][1] * __expf(-FOUR_LN2 * (fdx0 * fdx0 + fdy0 * fdy0))
          + params[i][4] * __expf(-FOUR_LN2 * (fdx1 * fdx1 + fdy1 * fdy1));
    } else {
      val = prob;
    }
    if (inb) {
      const int cls = q[(size_t)(i * 2 + b) * 65536 + (yy * 4) * 256 + (xx * 4)];
      atomicAdd(&accS[cls], val);
    }
  }
  __syncthreads();

  // ---------- phase 5: write output ----------
  if (t < NCLS) {
    const float sc = (t == 0) ? 1.0f : 1.15f;
    out[(size_t)(b * NCLS + t) * HW + (y * W + x)] = accS[t] * sc;
  }
}

}  // namespace

extern "C" void kernel_launch(void* const* d_in, const int* in_sizes, int n_in,
                              void* d_out, int out_size, void* d_ws, size_t ws_size,
                              hipStream_t stream) {
  const float* fr = (const float*)d_in[0];   // feats_r
  const float* ft = (const float*)d_in[1];   // feats_t
  const int*   q  = (const int*)d_in[2];     // quantized_r
  float* out = (float*)d_out;
  colorizer_kernel<<<dim3(2 * HW), dim3(384), 0, stream>>>(fr, ft, q, out);
}

// Round 5
// 86.524 us; speedup vs baseline: 2.6326x; 2.6326x over previous
//
#include <hip/hip_runtime.h>
#include <math.h>

namespace {

constexpr int RAD  = 6;
constexpr int P    = 13;
constexpr int NWIN = 169;   // P*P
constexpr int NTOT = 338;   // 2 refs * NWIN
constexpr int NCH  = 128;
constexpr int NCLS = 32;
constexpr int W    = 64;
constexpr int HW   = 4096;
constexpr float FOUR_LN2 = 2.772588722239781f;

// ---- kernel A tiling ----
constexpr int TX    = 32;            // pixels per block (half row)
constexpr int CHUNK = 4;             // channels per stage
constexpr int PW    = 48;            // patch width: 44 used + 4 pad (16B aligned rows)
constexpr int PR    = 13;            // patch rows (dy)
constexpr int FRELEMS = CHUNK * PR * PW;   // 2496
constexpr int NCHUNK  = NCH / CHUNK;       // 32

__device__ __forceinline__ bool better(float va, int ia, float vb, int ib) {
  return (va > vb) || ((va == vb) && (ia < ib));
}

// ================= Kernel A: correlation volume =================
// grid: ((b*2+i)*64 + y)*2 + xh   (512 blocks), 128 threads
// vol layout: [b*2+i][m (169)][y][x]  (float)
__global__ __launch_bounds__(128) void corr_kernel(
    const float* __restrict__ fr,   // [2][2][128][64][64]  (nref,b,c,y,x)
    const float* __restrict__ ft,   // [2][128][64][64]
    float* __restrict__ vol) {
  const int blk = blockIdx.x;
  const int xh = blk & 1;
  const int y  = (blk >> 1) & 63;
  const int bi = blk >> 7;             // b*2+i
  const int b  = bi >> 1;
  const int ii = bi & 1;
  const int x0 = xh * TX;
  const int t  = threadIdx.x;

  __shared__ __align__(16) float frbuf[2][FRELEMS];
  __shared__ __align__(16) float ftbuf[2][CHUNK * TX];   // 128 == blockDim

  const int xg = t & 7;                // x-quad within half row
  const int dy = t >> 3;               // 0..12 valid when t<104
  const bool comp = (t < 104);

  // fr outer layout is [nref][b] -> index ii*2+b  (NOT bi)
  const float* frbase = fr + (size_t)((ii * 2 + b) * NCH) * HW;
  const float* ftbase = ft + (size_t)(b * NCH) * HW + y * W + x0;

  float acc[13][4];
  #pragma unroll
  for (int dx = 0; dx < 13; ++dx)
    #pragma unroll
    for (int k = 0; k < 4; ++k) acc[dx][k] = 0.f;

  float rg[20];
  float rft;

  // --- stage load: chunk starting at channel c0 -> registers ---
  auto stage_load = [&](int c0) {
    #pragma unroll
    for (int u = 0; u < 20; ++u) {
      const int e = t + u * 128;
      float v = 0.f;
      if (e < FRELEMS) {
        const int cc  = e / (PR * PW);
        const int rem = e - cc * (PR * PW);
        const int r   = rem / PW;
        const int xc  = rem - r * PW;
        const int yy  = y + r - RAD;
        const int xx  = x0 - RAD + xc;
        if ((unsigned)yy < 64u && (unsigned)xx < 64u && xc < 44)
          v = frbase[(size_t)(c0 + cc) * HW + yy * W + xx];
      }
      rg[u] = v;
    }
    const int cc = t >> 5;             // 0..3
    const int xl = t & 31;
    rft = ftbase[(size_t)(c0 + cc) * HW + xl];
  };
  auto stage_write = [&](int s) {
    #pragma unroll
    for (int u = 0; u < 20; ++u) {
      const int e = t + u * 128;
      if (e < FRELEMS) frbuf[s][e] = rg[u];
    }
    ftbuf[s][t] = rft;
  };

  stage_load(0);
  stage_write(0);
  __syncthreads();

  for (int k = 0; k < NCHUNK; ++k) {
    const int cur = k & 1;
    if (k < NCHUNK - 1) stage_load((k + 1) * CHUNK);   // issue early (T14)
    if (comp) {
      #pragma unroll
      for (int cc = 0; cc < CHUNK; ++cc) {
        const float* fp = &frbuf[cur][(cc * PR + dy) * PW + xg * 4];
        float w[16];
        #pragma unroll
        for (int j = 0; j < 4; ++j) {
          const float4 q4 = *(const float4*)(fp + 4 * j);
          w[4 * j] = q4.x; w[4 * j + 1] = q4.y; w[4 * j + 2] = q4.z; w[4 * j + 3] = q4.w;
        }
        const float4 tq = *(const float4*)(&ftbuf[cur][cc * TX + xg * 4]);
        const float tqa[4] = {tq.x, tq.y, tq.z, tq.w};
        #pragma unroll
        for (int dx = 0; dx < 13; ++dx)
          #pragma unroll
          for (int kk = 0; kk < 4; ++kk)
            acc[dx][kk] = fmaf(w[dx + kk], tqa[kk], acc[dx][kk]);
      }
    }
    __syncthreads();
    if (k < NCHUNK - 1) {
      stage_write(cur ^ 1);
    }
    __syncthreads();
  }

  if (comp) {
    const int x4 = x0 + xg * 4;
    float* vp = vol + (size_t)(bi * NWIN + dy * 13) * HW + y * W + x4;
    #pragma unroll
    for (int dx = 0; dx < 13; ++dx) {
      float4 st = make_float4(acc[dx][0], acc[dx][1], acc[dx][2], acc[dx][3]);
      *(float4*)(vp + (size_t)dx * HW) = st;
    }
  }
}

// ================= Kernel B: softmax + top2 + heat + scatter =================
__global__ __launch_bounds__(384) void post_kernel(
    const float* __restrict__ vol,  // [2*2][169][64][64]
    const int*  __restrict__ q,     // [2][2][1][256][256]
    float* __restrict__ out) {      // [2][32][64][64]
  const int pix = blockIdx.x;          // b*4096 + y*64 + x
  const int b = pix >> 12;
  const int y = (pix >> 6) & 63;
  const int x = pix & 63;
  const int t = threadIdx.x;
  const int wid  = t >> 6;
  const int lane = t & 63;

  __shared__ float s[NTOT];
  __shared__ float wred[6];
  __shared__ float accS[NCLS];
  __shared__ float params[2][8];

  if (t < NCLS) accS[t] = 0.f;

  const bool act = (t < NTOT);
  const int i  = (t >= NWIN) ? 1 : 0;
  const int m  = t - i * NWIN;
  const int dy = m / P;
  const int dx = m - dy * P;
  const int yy = y + dy - RAD;
  const int xx = x + dx - RAD;
  const bool inb = ((unsigned)yy < 64u) && ((unsigned)xx < 64u);

  // ---------- phase 1: load correlation value ----------
  float dot = 0.f;
  if (act) dot = vol[(size_t)((b * 2 + i) * NWIN + m) * HW + y * W + x];

  // ---------- phase 2: joint softmax over 338 ----------
  const float v = act ? dot : -INFINITY;
  float lmax = v;
  for (int off = 32; off > 0; off >>= 1)
    lmax = fmaxf(lmax, __shfl_xor(lmax, off));
  if (lane == 0) wred[wid] = lmax;
  __syncthreads();
  const float gmax = fmaxf(fmaxf(fmaxf(wred[0], wred[1]), fmaxf(wred[2], wred[3])),
                           fmaxf(wred[4], wred[5]));
  const float e = act ? __expf(v - gmax) : 0.f;
  float lsum = e;
  for (int off = 32; off > 0; off >>= 1)
    lsum += __shfl_xor(lsum, off);
  __syncthreads();
  if (lane == 0) wred[wid] = lsum;
  __syncthreads();
  const float gsum = wred[0] + wred[1] + wred[2] + wred[3] + wred[4] + wred[5];
  const float prob = e / gsum;
  if (act) s[t] = prob;
  __syncthreads();

  // ---------- phase 3: per-ref top-2 (waves 0,1), stable tie-break ----------
  if (wid < 2) {
    const int ii = wid;
    float v1 = -1.f, v2 = -1.f;
    int i1 = 1 << 20, i2 = 1 << 20;
    for (int mm = lane; mm < NWIN; mm += 64) {
      const float pv = s[ii * NWIN + mm];
      if (better(pv, mm, v1, i1)) { v2 = v1; i2 = i1; v1 = pv; i1 = mm; }
      else if (better(pv, mm, v2, i2)) { v2 = pv; i2 = mm; }
    }
    for (int off = 32; off > 0; off >>= 1) {
      const float u1 = __shfl_xor(v1, off); const int j1 = __shfl_xor(i1, off);
      const float u2 = __shfl_xor(v2, off); const int j2 = __shfl_xor(i2, off);
      if (better(u1, j1, v1, i1)) {
        float nv2; int ni2;
        if (better(v1, i1, u2, j2)) { nv2 = v1; ni2 = i1; }
        else                        { nv2 = u2; ni2 = j2; }
        v1 = u1; i1 = j1; v2 = nv2; i2 = ni2;
      } else if (better(u1, j1, v2, i2)) {
        v2 = u1; i2 = j1;
      }
    }
    if (lane == 0) {
      const float e1 = __expf(v1);
      const float e2 = __expf(v2);
      const float rs = 1.f / (e1 + e2);
      params[ii][0] = (v1 > 0.1f) ? 1.f : 0.f;
      params[ii][1] = e1 * rs;
      params[ii][2] = (float)(i1 % P);
      params[ii][3] = (float)(i1 / P);
      params[ii][4] = e2 * rs;
      params[ii][5] = (float)(i2 % P);
      params[ii][6] = (float)(i2 / P);
    }
  }
  __syncthreads();

  // ---------- phase 4: corr2 + label scatter ----------
  if (act) {
    float val;
    if (params[i][0] != 0.f) {
      const float fdx0 = (float)dx - params[i][2];
      const float fdy0 = (float)dy - params[i][3];
      const float fdx1 = (float)dx - params[i][5];
      const float fdy1 = (float)dy - params[i][6];
      val = params[i][1] * __expf(-FOUR_LN2 * (fdx0 * fdx0 + fdy0 * fdy0))
          + params[i][4] * __expf(-FOUR_LN2 * (fdx1 * fdx1 + fdy1 * fdy1));
    } else {
      val = prob;
    }
    if (inb) {
      const int cls = q[(size_t)(i * 2 + b) * 65536 + (yy * 4) * 256 + (xx * 4)];
      atomicAdd(&accS[cls], val);
    }
  }
  __syncthreads();

  // ---------- phase 5: write output ----------
  if (t < NCLS) {
    const float sc = (t == 0) ? 1.0f : 1.15f;
    out[(size_t)(b * NCLS + t) * HW + (y * W + x)] = accS[t] * sc;
  }
}

}  // namespace

extern "C" void kernel_launch(void* const* d_in, const int* in_sizes, int n_in,
                              void* d_out, int out_size, void* d_ws, size_t ws_size,
                              hipStream_t stream) {
  const float* fr = (const float*)d_in[0];   // feats_r
  const float* ft = (const float*)d_in[1];   // feats_t
  const int*   q  = (const int*)d_in[2];     // quantized_r
  float* out = (float*)d_out;
  float* vol = (float*)d_ws;                 // 2*2*169*4096 floats = 11.1 MB

  corr_kernel<<<dim3(2 * 2 * 64 * 2), dim3(128), 0, stream>>>(fr, ft, vol);
  post_kernel<<<dim3(2 * HW), dim3(384), 0, stream>>>(vol, q, out);
}